// Round 9
// baseline (658.583 us; speedup 1.0000x reference)
//
#include <hip/hip_runtime.h>
#include <stdint.h>

typedef _Float16 f16;
typedef _Float16 f16x8 __attribute__((ext_vector_type(8)));
typedef _Float16 f16x4 __attribute__((ext_vector_type(4)));
typedef float f32x4 __attribute__((ext_vector_type(4)));

__global__ __launch_bounds__(256) void zerof(float* __restrict__ p, int n) {
    int i = blockIdx.x * 256 + threadIdx.x;
    if (i < n) p[i] = 0.f;
}

__global__ __launch_bounds__(256) void cvt16(const float* __restrict__ in,
                                             f16* __restrict__ o, long n) {
    long i = (long)blockIdx.x * 256 + threadIdx.x;
    if (i < n) o[i] = (f16)in[i];
}

// Pack w [27][Cin][Cout] fp32 into MFMA B-fragment order:
// unit i = ((ktap*NCT + ct)*4 + kk)*64 + lane (16 B units, 8 f16).
// lane frag: col = ct*16 + (lane&15), ci = h*128 + kk*32 + (lane>>4)*8 + j; ktap = k*KH+h.
__global__ __launch_bounds__(256) void packB(const float* __restrict__ w,
                                             f16* __restrict__ wp,
                                             int Cin, int Cout, int KH) {
    const int NCT = Cout / 16;
    const long total = 27L * KH * NCT * 4 * 64;
    long i = (long)blockIdx.x * 256 + threadIdx.x;
    if (i >= total) return;
    int lane = (int)(i & 63);
    int kk   = (int)((i >> 6) & 3);
    long r   = i >> 8;
    int ct   = (int)(r % NCT);
    long kt  = r / NCT;
    int k    = (int)(kt / KH);
    int h    = (int)(kt % KH);
    int ci0  = h * 128 + kk * 32 + (lane >> 4) * 8;
    int co   = ct * 16 + (lane & 15);
    f16x8 v;
#pragma unroll
    for (int j = 0; j < 8; j++)
        v[j] = (f16)w[((long)k * Cin + ci0 + j) * Cout + co];
    ((f16x8*)wp)[i] = v;
}

// Dense implicit 3x3x3 conv with z-plane weight reuse.
// Block tile: 32 sites (2y x 16x) x ALL output planes x full COUT.
//  - A: halo slabs (4y x 18x) for ALL input planes staged ONCE at kernel start
//    via vector loads (no DMA gather) -> ONE barrier per kernel.
//  - B: register double-buffered, one tap lookahead, from fragment-packed wp
//    (coalesced 1 KB loads). Each B-frag feeds 2-3 output planes x 2 row tiles.
//  LDS <= 55296 B -> 2 blocks/CU. Grid = 288 for all layers.
// LAYER 0: 1 in-plane, CIN=256 (KH=2), 3 out-planes, p = 1-dz, COUT=128
// LAYER 1: 3 in-planes, j = p+dz,   3 out-planes, COUT=128
// LAYER 2: 3 in-planes, j = p+dz-1, 5 out-planes, COUT=32
template <int LAYER>
__global__ __launch_bounds__(256) void conv_dense(
    const f16* __restrict__ fin, const f16* __restrict__ wp,
    float* __restrict__ out, float* __restrict__ part) {
    constexpr int COUT  = (LAYER == 2) ? 32 : 128;
    constexpr int NCT   = COUT / 16;
    constexpr int NPI   = (LAYER == 0) ? 1 : 3;     // input planes
    constexpr int NPO   = (LAYER == 2) ? 5 : 3;     // output planes
    constexpr int INRB  = (LAYER == 0) ? 512 : 256; // input row bytes
    constexpr int UROW  = INRB / 16;                // 16-B units per row
    constexpr int NKT   = (LAYER == 0) ? 54 : 27;   // tap(*half) count
    constexpr int CT    = (LAYER == 2) ? 1 : 2;     // col tiles per wave
    __shared__ char ldsA[NPI * 72 * INRB];          // 36864 / 55296 / 55296

    const int b = blockIdx.x;
    const int y0 = (b / 6) * 2;
    const int x0 = (b % 6) * 16;
    const int tid = threadIdx.x;
    const int lane = tid & 63;
    const int wave = tid >> 6;
    const int q = lane >> 4;
    const int r16 = lane & 15;
    const int ctbase = (LAYER == 2) ? (wave & 1) : wave * 2;  // global col tile
    const int yw = (LAYER == 2) ? (wave >> 1) : 0;            // L2: wave's y row

    // ---- stage ALL input-plane halo slabs once (vector loads, 1 barrier) ----
    constexpr int NU = NPI * 72 * UROW;
    for (int u = tid; u < NU; u += 256) {
        int c = u % UROW;
        int site = (u / UROW) % 72;
        int pl = u / (72 * UROW);
        int sy = site / 18, sx = site % 18;
        int y = y0 - 1 + sy, x = x0 - 1 + sx;
        int su;
        if (LAYER == 0) su = (c & 16) + ((c & 15) ^ (site & 7));
        else            su = c ^ (site & 7);
        int4 v = int4{0, 0, 0, 0};
        if (((unsigned)y < 96u) & ((unsigned)x < 96u))
            v = *(const int4*)((const char*)fin +
                               ((long)(pl * 9216 + y * 96 + x)) * INRB + su * 16);
        *(int4*)(ldsA + (pl * 72 + site) * INRB + c * 16) = v;
    }

    const f16x8* wpv = (const f16x8*)wp;
    f16x8 Ba[CT][4], Bb[CT][4];
    auto loadB = [&](f16x8 (&B)[CT][4], int kt) {
        const long base = ((long)kt * NCT + ctbase) * 4 * 64 + lane;
#pragma unroll
        for (int c = 0; c < CT; c++)
#pragma unroll
            for (int kk = 0; kk < 4; kk++)
                B[c][kk] = wpv[base + (c * 4 + kk) * 64];
    };

    f32x4 acc[NPO][CT * 2];   // L0/L1: [p][tr*2+c]; L2: [p][0]
#pragma unroll
    for (int p = 0; p < NPO; p++)
#pragma unroll
        for (int i = 0; i < CT * 2; i++) acc[p][i] = f32x4{0.f, 0.f, 0.f, 0.f};

    loadB(Ba, 0);
    __syncthreads();   // slabs staged; B0 drains with first use

    for (int kt = 0; kt < NKT; kt++) {
        if (kt + 1 < NKT) {
            if (kt & 1) loadB(Ba, kt + 1);
            else        loadB(Bb, kt + 1);
        }
        auto& B = (kt & 1) ? Bb : Ba;
        const int k  = (LAYER == 0) ? (kt >> 1) : kt;
        const int h  = (LAYER == 0) ? (kt & 1) : 0;
        const int dz = k / 9 - 1;
        const int i9 = k - (dz + 1) * 9;
        const int dy = i9 / 3 - 1;
        const int dx = i9 - (dy + 1) * 3 - 1;
#pragma unroll
        for (int kk = 0; kk < 4; kk++) {
            const int c16 = kk * 4 + q;
            if (LAYER == 0) {
                const int p = 1 - dz;   // single valid output plane
#pragma unroll
                for (int tr = 0; tr < 2; tr++) {
                    int site = (tr + 1 + dy) * 18 + 1 + dx + r16;
                    f16x8 A = *(const f16x8*)(ldsA + site * 512 + h * 256 +
                                              ((c16 ^ (site & 7)) << 4));
#pragma unroll
                    for (int c = 0; c < CT; c++) {
#pragma unroll
                        for (int pp = 0; pp < 3; pp++)
                            if (pp == p)
                                acc[pp][tr * 2 + c] = __builtin_amdgcn_mfma_f32_16x16x32_f16(
                                    A, B[c][kk], acc[pp][tr * 2 + c], 0, 0, 0);
                    }
                }
            } else if (LAYER == 1) {
#pragma unroll
                for (int p = 0; p < 3; p++) {
                    const int j = p + dz;
                    if ((unsigned)j >= 3u) continue;   // block-uniform
#pragma unroll
                    for (int tr = 0; tr < 2; tr++) {
                        int site = (tr + 1 + dy) * 18 + 1 + dx + r16;
                        f16x8 A = *(const f16x8*)(ldsA + j * 18432 + site * 256 +
                                                  ((c16 ^ (site & 7)) << 4));
#pragma unroll
                        for (int c = 0; c < CT; c++)
                            acc[p][tr * 2 + c] = __builtin_amdgcn_mfma_f32_16x16x32_f16(
                                A, B[c][kk], acc[p][tr * 2 + c], 0, 0, 0);
                    }
                }
            } else {
#pragma unroll
                for (int p = 0; p < 5; p++) {
                    const int j = p + dz - 1;
                    if ((unsigned)j >= 3u) continue;
                    int site = (yw + 1 + dy) * 18 + 1 + dx + r16;
                    f16x8 A = *(const f16x8*)(ldsA + j * 18432 + site * 256 +
                                              ((c16 ^ (site & 7)) << 4));
                    acc[p][0] = __builtin_amdgcn_mfma_f32_16x16x32_f16(
                        A, B[0][kk], acc[p][0], 0, 0, 0);
                }
            }
        }
    }

    // ---- epilogue: C write (row=q*4+r, col=r16) + slotted BN stats ----
    const int slot = b & 63;
    if (LAYER == 2) {
        const int col = ctbase * 16 + r16;
        float s = 0.f, ss = 0.f;
#pragma unroll
        for (int p = 0; p < 5; p++)
#pragma unroll
            for (int r = 0; r < 4; r++) {
                float v = acc[p][0][r];
                out[((long)(p * 9216 + (y0 + yw) * 96 + x0 + q * 4 + r)) * 32 + col] = v;
                s += v;
                ss = fmaf(v, v, ss);
            }
        s += __shfl_xor(s, 16); s += __shfl_xor(s, 32);
        ss += __shfl_xor(ss, 16); ss += __shfl_xor(ss, 32);
        if (q == 0) {
            atomicAdd(&part[(long)col * 64 + slot], s);
            atomicAdd(&part[(long)(32 + col) * 64 + slot], ss);
        }
    } else {
#pragma unroll
        for (int c = 0; c < CT; c++) {
            const int col = (ctbase + c) * 16 + r16;
            float s = 0.f, ss = 0.f;
#pragma unroll
            for (int p = 0; p < 3; p++)
#pragma unroll
                for (int tr = 0; tr < 2; tr++)
#pragma unroll
                    for (int r = 0; r < 4; r++) {
                        float v = acc[p][tr * 2 + c][r];
                        out[((long)(p * 9216 + (y0 + tr) * 96 + x0 + q * 4 + r)) * 128 + col] = v;
                        s += v;
                        ss = fmaf(v, v, ss);
                    }
            s += __shfl_xor(s, 16); s += __shfl_xor(s, 32);
            ss += __shfl_xor(ss, 16); ss += __shfl_xor(ss, 32);
            if (q == 0) {
                atomicAdd(&part[(long)col * 64 + slot], s);
                atomicAdd(&part[(long)(128 + col) * 64 + slot], ss);
            }
        }
    }
}

// part [n2c][64] -> stats[n2c]
__global__ __launch_bounds__(256) void reduce_stats(const float* __restrict__ part,
                                                    float* __restrict__ stats, int n2c) {
    int t = blockIdx.x * 256 + threadIdx.x;
    if (t >= n2c) return;
    const float4* pv = (const float4*)(part + (long)t * 64);
    float s = 0.f;
#pragma unroll
    for (int i = 0; i < 16; i++) {
        float4 v = pv[i];
        s += v.x + v.y + v.z + v.w;
    }
    stats[t] = s;
}

// BN(train) + optional residual + ReLU, 4 elems/thread.
__global__ __launch_bounds__(256) void bn_apply4(
    const float4* __restrict__ f, const float* __restrict__ sums,
    const float* __restrict__ g, const float* __restrict__ bta,
    const f16x4* __restrict__ idn, f16* __restrict__ outh,
    float4* __restrict__ outf, long n4, int C, float invM) {
    long i = (long)blockIdx.x * 256 + threadIdx.x;
    if (i >= n4) return;
    int col0 = (int)((i * 4) & (C - 1));
    float4 v = f[i];
    float r[4] = {v.x, v.y, v.z, v.w};
    f16x4 id = {};
    if (idn) id = idn[i];
    f16x4 ho;
#pragma unroll
    for (int j = 0; j < 4; j++) {
        int c = col0 + j;
        float mu = sums[c] * invM;
        float var = sums[C + c] * invM - mu * mu;
        var = fmaxf(var, 0.f);
        float sc = g[c] * rsqrtf(var + 1e-5f);
        float x = (r[j] - mu) * sc + bta[c];
        if (idn) x += (float)id[j];
        x = fmaxf(x, 0.f);
        r[j] = x;
        ho[j] = (f16)x;
    }
    if (outf) outf[i] = make_float4(r[0], r[1], r[2], r[3]);
    else *(f16x4*)(outh + i * 4) = ho;
}

extern "C" void kernel_launch(void* const* d_in, const int* in_sizes, int n_in,
                              void* d_out, int out_size, void* d_ws, size_t ws_size,
                              hipStream_t stream) {
    (void)n_in; (void)out_size; (void)ws_size;
    const float* x    = (const float*)d_in[0];
    const float* w_s1 = (const float*)d_in[1];
    const float* g_s1 = (const float*)d_in[2];
    const float* b_s1 = (const float*)d_in[3];
    const float* w11  = (const float*)d_in[4];
    const float* g11  = (const float*)d_in[5];
    const float* b11  = (const float*)d_in[6];
    const float* w12  = (const float*)d_in[7];
    const float* g12  = (const float*)d_in[8];
    const float* b12  = (const float*)d_in[9];
    const float* w21  = (const float*)d_in[10];
    const float* g21  = (const float*)d_in[11];
    const float* b21  = (const float*)d_in[12];
    const float* w22  = (const float*)d_in[13];
    const float* g22  = (const float*)d_in[14];
    const float* b22  = (const float*)d_in[15];
    const float* w_s2 = (const float*)d_in[16];
    const float* g_s2 = (const float*)d_in[17];
    const float* b_s2 = (const float*)d_in[18];

    const int N0 = in_sizes[0] / 256;   // 9216
    const int M1 = in_sizes[19] / 27;   // 27648
    const int M2 = in_sizes[21] / 27;   // 46080

    char* base = (char*)d_ws;
    size_t off = 0;
    auto alloc = [&](size_t bytes) -> char* {
        off = (off + 255) & ~(size_t)255;
        char* p = base + off;
        off += bytes;
        return p;
    };
    f16* xh  = (f16*)alloc((size_t)N0 * 256 * 2);
    f16* w1  = (f16*)alloc(27UL * 2 * 8 * 4 * 64 * 16);   // L0 pack (KH=2)
    f16* wa1 = (f16*)alloc(27UL * 8 * 4 * 64 * 16);
    f16* wa2 = (f16*)alloc(27UL * 8 * 4 * 64 * 16);
    f16* wb1 = (f16*)alloc(27UL * 8 * 4 * 64 * 16);
    f16* wb2 = (f16*)alloc(27UL * 8 * 4 * 64 * 16);
    f16* w2  = (f16*)alloc(27UL * 2 * 4 * 64 * 16);       // L2 pack (NCT=2)
    f16* fA  = (f16*)alloc((size_t)M1 * 128 * 2);
    f16* fB  = (f16*)alloc((size_t)M1 * 128 * 2);
    float* cbuf  = (float*)alloc((size_t)M1 * 128 * 4);   // covers M2*32 too
    float* parts = (float*)alloc((5UL * 16384 + 4096) * 4);
    float* stats = (float*)alloc(1344UL * 4);

    zerof<<<(5 * 16384 + 4096 + 255) / 256, 256, 0, stream>>>(parts, 5 * 16384 + 4096);

    long nx = (long)N0 * 256;
    cvt16<<<(int)((nx + 255) / 256), 256, 0, stream>>>(x, xh, nx);
    packB<<<(27 * 2 * 8 * 4 * 64 + 255) / 256, 256, 0, stream>>>(w_s1, w1, 256, 128, 2);
    packB<<<(27 * 8 * 4 * 64 + 255) / 256, 256, 0, stream>>>(w11, wa1, 128, 128, 1);
    packB<<<(27 * 8 * 4 * 64 + 255) / 256, 256, 0, stream>>>(w12, wa2, 128, 128, 1);
    packB<<<(27 * 8 * 4 * 64 + 255) / 256, 256, 0, stream>>>(w21, wb1, 128, 128, 1);
    packB<<<(27 * 8 * 4 * 64 + 255) / 256, 256, 0, stream>>>(w22, wb2, 128, 128, 1);
    packB<<<(27 * 2 * 4 * 64 + 255) / 256, 256, 0, stream>>>(w_s2, w2, 128, 32, 1);

    const float inv1 = 1.f / (float)M1, inv2 = 1.f / (float)M2;
    const int gc = 288;                 // 48 y-tiles x 6 x-blocks, all planes in-block
    const long n4a = (long)M1 * 128 / 4;
    const long n4b = (long)M2 * 32 / 4;
    const int ga = (int)((n4a + 255) / 256);
    const int gb = (int)((n4b + 255) / 256);

    float* P0 = parts;
    float* P1 = parts + 16384;
    float* P2 = parts + 2 * 16384;
    float* P3 = parts + 3 * 16384;
    float* P4 = parts + 4 * 16384;
    float* P5 = parts + 5 * 16384;

    // L1: spconv1 (256 -> 128)
    conv_dense<0><<<gc, 256, 0, stream>>>(xh, w1, cbuf, P0);
    reduce_stats<<<1, 256, 0, stream>>>(P0, stats, 256);
    bn_apply4<<<ga, 256, 0, stream>>>((float4*)cbuf, stats, g_s1, b_s1,
                                      nullptr, fA, nullptr, n4a, 128, inv1);
    // Block 1
    conv_dense<1><<<gc, 256, 0, stream>>>(fA, wa1, cbuf, P1);
    reduce_stats<<<1, 256, 0, stream>>>(P1, stats + 256, 256);
    bn_apply4<<<ga, 256, 0, stream>>>((float4*)cbuf, stats + 256, g11, b11,
                                      nullptr, fB, nullptr, n4a, 128, inv1);
    conv_dense<1><<<gc, 256, 0, stream>>>(fB, wa2, cbuf, P2);
    reduce_stats<<<1, 256, 0, stream>>>(P2, stats + 512, 256);
    bn_apply4<<<ga, 256, 0, stream>>>((float4*)cbuf, stats + 512, g12, b12,
                                      (const f16x4*)fA, fA, nullptr, n4a, 128, inv1);
    // Block 2
    conv_dense<1><<<gc, 256, 0, stream>>>(fA, wb1, cbuf, P3);
    reduce_stats<<<1, 256, 0, stream>>>(P3, stats + 768, 256);
    bn_apply4<<<ga, 256, 0, stream>>>((float4*)cbuf, stats + 768, g21, b21,
                                      nullptr, fB, nullptr, n4a, 128, inv1);
    conv_dense<1><<<gc, 256, 0, stream>>>(fB, wb2, cbuf, P4);
    reduce_stats<<<1, 256, 0, stream>>>(P4, stats + 1024, 256);
    bn_apply4<<<ga, 256, 0, stream>>>((float4*)cbuf, stats + 1024, g22, b22,
                                      (const f16x4*)fA, fA, nullptr, n4a, 128, inv1);
    // L6: spconv2 (128 -> 32), final fp32 output
    conv_dense<2><<<gc, 256, 0, stream>>>(fA, w2, cbuf, P5);
    reduce_stats<<<1, 256, 0, stream>>>(P5, stats + 1280, 64);
    bn_apply4<<<gb, 256, 0, stream>>>((float4*)cbuf, stats + 1280, g_s2, b_s2,
                                      nullptr, nullptr, (float4*)d_out, n4b, 32, inv2);
}